// Round 7
// baseline (113.128 us; speedup 1.0000x reference)
//
#include <hip/hip_runtime.h>
#include <hip/hip_bf16.h>
#include <math.h>

// NTXent loss, N=8192 rows, D=128.
// loss = mean_i [ log(sum_{j!=i} exp(2*cos_ij)) - 2*cos_{i,partner} ]
// R7: R6 structure (528 upper-triangle 256x256 tiles, 3 blocks/CU, A in
// regs, B glds->LDS dbuf) with 64-col chunks: barriers per block 8 -> 4
// (each __syncthreads forces a vmcnt(0) drain of the glds queue). LDS
// 2x16KB + colsum = 33 KB/block, still 3 blocks/CU.

typedef __attribute__((ext_vector_type(8))) short bf16x8;   // 8 bf16 = 4 VGPRs
typedef __attribute__((ext_vector_type(4))) float f32x4;

#define NROWS 8192
#define DDIM  128
#define BHALF 4096
#define CHUNK 64                    // sim-cols per LDS buffer
#define NT    32                    // 32x32 grid of 256x256 tiles
#define NBLK  528                   // 32*33/2 upper-triangle tiles
// zn scaled by sqrt(2/ln2): acc = (2/ln2)*cos, exp(2cos) = exp2(acc)
#define SQRT_E2S 1.6986435980707531f
#define TWO_LN2  1.3862943611198906f
#define EXPDIAG  7.38905609893065f

static __device__ __forceinline__ unsigned short f2bf(float f) {
  unsigned int u = __float_as_uint(f);
  unsigned int r = (u + 0x7fffu + ((u >> 16) & 1u)) >> 16;   // RNE
  return (unsigned short)r;
}

static __device__ __forceinline__ void glds16(const unsigned short* g, unsigned short* l) {
  __builtin_amdgcn_global_load_lds((const __attribute__((address_space(1))) unsigned int*)g,
                                   (__attribute__((address_space(3))) unsigned int*)l,
                                   16, 0, 0);
}

// ---- Kernel 1: normalize (scaled) + fp32 pair-dots + zero sums/out -------
// Block b: waves 0,1 -> rows 2b,2b+1 (zi); waves 2,3 -> their partners (zj).
__global__ void norm_kernel(const float* __restrict__ zi, const float* __restrict__ zj,
                            unsigned short* __restrict__ zn,
                            float* __restrict__ row_sums, float* __restrict__ pos,
                            float* __restrict__ out) {
  __shared__ float2 xbuf[2][64];
  int wave = threadIdx.x >> 6;
  int lane = threadIdx.x & 63;
  int pi   = blockIdx.x * 2 + (wave & 1);           // pair index
  int row  = pi + (wave >> 1) * BHALF;
  const float* src = (row < BHALF) ? (zi + (size_t)row * DDIM)
                                   : (zj + (size_t)(row - BHALF) * DDIM);
  float2 v = *(const float2*)(src + 2 * lane);
  float ss = v.x * v.x + v.y * v.y;
  #pragma unroll
  for (int off = 1; off < 64; off <<= 1) ss += __shfl_xor(ss, off);
  float scale = SQRT_E2S / fmaxf(sqrtf(ss), 1e-8f);
  v.x *= scale; v.y *= scale;
  unsigned int lo = f2bf(v.x), hi = f2bf(v.y);
  ((unsigned int*)(zn + (size_t)row * DDIM))[lane] = lo | (hi << 16);

  if (wave >= 2) xbuf[wave - 2][lane] = v;
  __syncthreads();
  if (wave < 2) {                                    // d = (2/ln2)*cos(i, i+B)
    float2 w = xbuf[wave][lane];
    float d = v.x * w.x + v.y * w.y;
    #pragma unroll
    for (int off = 1; off < 64; off <<= 1) d += __shfl_xor(d, off);
    if (lane == 0) pos[pi] = d;
  }
  if (threadIdx.x < 4) row_sums[blockIdx.x * 4 + threadIdx.x] = 0.0f;
  if (blockIdx.x == 0 && threadIdx.x == 4) out[0] = 0.0f;
}

// ---- Kernel 2: upper-triangle sim + exp + row/col sums -------------------
// 528 blocks (triangle map), 256x256 tiles, 4 waves x 64 rows, A in regs,
// B in 64-col chunks double-buffered via global_load_lds (XOR swizzle).
__global__ __launch_bounds__(256, 3)
void sim_kernel(const unsigned short* __restrict__ zn, float* __restrict__ row_sums) {
  __shared__ unsigned short lds[2 * CHUNK * DDIM];   // 2 x 16 KB
  __shared__ float colsum[256];

  // linear block id -> upper-triangle (tx <= ty) over NT x NT
  int t = blockIdx.x;
  int tx = (int)((65.0f - sqrtf((float)(4225 - 8 * t))) * 0.5f);
  while ((tx + 1) * NT - ((tx + 1) * tx) / 2 <= t) ++tx;
  while (tx * NT - (tx * (tx - 1)) / 2 > t) --tx;
  const int ty = t - (tx * NT - (tx * (tx - 1)) / 2) + tx;
  const bool diag = (tx == ty);

  const int wave = threadIdx.x >> 6;
  const int lane = threadIdx.x & 63;
  const int l15  = lane & 15;
  const int quad = lane >> 4;

  const int row_base = tx * 256 + wave * 64;
  const int col_base = ty * 256;

  colsum[threadIdx.x] = 0.0f;

  // A fragments: A[m=l15][k=quad*8+j], 4 mi-tiles x 4 k-frags = 64 VGPRs
  bf16x8 a[4][4];
  const unsigned short* abase = zn + (size_t)(row_base + l15) * DDIM + quad * 8;
  #pragma unroll
  for (int mi = 0; mi < 4; ++mi)
    #pragma unroll
    for (int kf = 0; kf < 4; ++kf)
      a[mi][kf] = *(const bf16x8*)(abase + mi * 16 * DDIM + kf * 32);

  float rs[4][4];
  #pragma unroll
  for (int mi = 0; mi < 4; ++mi)
    #pragma unroll
    for (int r = 0; r < 4; ++r) rs[mi][r] = 0.0f;

  // Staging: buffer = 64 B-rows x 16 chunks of 16B (1024 slots); slot t2 ->
  // row t2>>4, chunk (t2&15)^(row&15) [XOR]. Four 256-lane issues s=0..3
  // cover slots s*256 + wave*64 + lane.
  const int t0 = wave * 64 + lane;
  int rr[4], cc[4];
  #pragma unroll
  for (int s = 0; s < 4; ++s) {
    rr[s] = (t0 + s * 256) >> 4;
    cc[s] = (t0 & 15) ^ (rr[s] & 15);
  }
  const unsigned short* gst[4];
  #pragma unroll
  for (int s = 0; s < 4; ++s)
    gst[s] = zn + (size_t)(col_base + rr[s]) * DDIM + cc[s] * 8;

  int rdoff[4];
  #pragma unroll
  for (int kf = 0; kf < 4; ++kf)
    rdoff[kf] = l15 * DDIM + (((quad + 4 * kf) ^ l15) << 3);

  #pragma unroll
  for (int s = 0; s < 4; ++s)                        // prime chunk 0 -> buf 0
    glds16(gst[s], lds + s * 2048 + wave * 512);
  __syncthreads();

  for (int ch = 0; ch < 4; ++ch) {
    const int buf = ch & 1;
    if (ch < 3) {                                    // stage chunk ch+1
      unsigned short* lb = lds + ((ch + 1) & 1) * 8192;
      #pragma unroll
      for (int s = 0; s < 4; ++s)
        glds16(gst[s] + (size_t)(ch + 1) * CHUNK * DDIM, lb + s * 2048 + wave * 512);
    }
    const unsigned short* lb = lds + buf * 8192;
    #pragma unroll
    for (int ni = 0; ni < 4; ++ni) {
      bf16x8 b[4];
      #pragma unroll
      for (int kf = 0; kf < 4; ++kf)
        b[kf] = *(const bf16x8*)(lb + ni * 16 * DDIM + rdoff[kf]);
      f32x4 acc[4];
      #pragma unroll
      for (int mi = 0; mi < 4; ++mi) {
        f32x4 z = {0.0f, 0.0f, 0.0f, 0.0f};
        acc[mi] = __builtin_amdgcn_mfma_f32_16x16x32_bf16(a[mi][0], b[0], z, 0, 0, 0);
      }
      #pragma unroll
      for (int kf = 1; kf < 4; ++kf)
        #pragma unroll
        for (int mi = 0; mi < 4; ++mi)
          acc[mi] = __builtin_amdgcn_mfma_f32_16x16x32_bf16(a[mi][kf], b[kf], acc[mi], 0, 0, 0);
      // e feeds this row's sum and (off-diag) the transposed row via colsum.
      float cs = 0.0f;
      #pragma unroll
      for (int mi = 0; mi < 4; ++mi)
        #pragma unroll
        for (int r = 0; r < 4; ++r) {
          float e = __builtin_amdgcn_exp2f(acc[mi][r]);
          rs[mi][r] += e;
          cs += e;
        }
      if (!diag) {                                   // transpose contribution
        cs += __shfl_xor(cs, 16);
        cs += __shfl_xor(cs, 32);
        if (quad == 0)
          atomicAdd(&colsum[(ch * 4 + ni) * 16 + l15], cs);
      }
    }
    __syncthreads();
  }

  // Row side. C/D layout: col=l15, row=quad*4+reg.
  #pragma unroll
  for (int mi = 0; mi < 4; ++mi)
    #pragma unroll
    for (int r = 0; r < 4; ++r) {
      float v = rs[mi][r];
      v += __shfl_xor(v, 1);
      v += __shfl_xor(v, 2);
      v += __shfl_xor(v, 4);
      v += __shfl_xor(v, 8);
      if (l15 == 0)
        atomicAdd(&row_sums[row_base + mi * 16 + quad * 4 + r], v);
    }
  // Col side: one atomic per col per block (transposed rows).
  if (!diag)
    atomicAdd(&row_sums[col_base + threadIdx.x], colsum[threadIdx.x]);
}

// ---- Kernel 3: logs + mean (pos already fp32 from norm) ------------------
__global__ void finalize_kernel(const float* __restrict__ row_sums,
                                const float* __restrict__ pos,
                                float* __restrict__ out) {
  __shared__ float red[4];
  int i = blockIdx.x * 256 + threadIdx.x;            // grid 16 x 256 = 4096 pairs
  float si = row_sums[i] - EXPDIAG;
  float sp = row_sums[i + BHALF] - EXPDIAG;
  float v = logf(si) + logf(sp) - TWO_LN2 * pos[i];
  #pragma unroll
  for (int off = 1; off < 64; off <<= 1) v += __shfl_xor(v, off);
  int wave = threadIdx.x >> 6, lane = threadIdx.x & 63;
  if (lane == 0) red[wave] = v;
  __syncthreads();
  if (threadIdx.x == 0)
    atomicAdd(out, (red[0] + red[1] + red[2] + red[3]) * (1.0f / 8192.0f));
}

extern "C" void kernel_launch(void* const* d_in, const int* in_sizes, int n_in,
                              void* d_out, int out_size, void* d_ws, size_t ws_size,
                              hipStream_t stream) {
  const float* zi = (const float*)d_in[0];
  const float* zj = (const float*)d_in[1];
  char* ws = (char*)d_ws;
  unsigned short* zn = (unsigned short*)ws;                    // 2 MB
  float* row_sums = (float*)(ws + (size_t)NROWS * DDIM * 2);   // 32 KB
  float* pos      = (float*)(ws + (size_t)NROWS * DDIM * 2 + NROWS * 4);  // 16 KB
  float* out = (float*)d_out;

  norm_kernel<<<2048, 256, 0, stream>>>(zi, zj, zn, row_sums, pos, out);
  sim_kernel<<<NBLK, 256, 0, stream>>>(zn, row_sums);
  finalize_kernel<<<16, 256, 0, stream>>>(row_sums, pos, out);
}

// Round 8
// 84.044 us; speedup vs baseline: 1.3460x; 1.3460x over previous
//
#include <hip/hip_runtime.h>
#include <hip/hip_bf16.h>
#include <math.h>

// NTXent loss, N=8192 rows, D=128.
// loss = mean_i [ log(sum_{j!=i} exp(2*cos_ij)) - 2*cos_{i,partner} ]
// R8: verbatim revert to the R6 optimum (84.3 us). R7's CHUNK=64 variant
// tripped the register allocator (VGPR 84, 88 MB scratch writes, MfmaUtil
// 5.7%): A-frags spilled. R6 config: 528 upper-triangle 256x256 tiles,
// CHUNK=32 glds->LDS dbuf, A in regs, 3 blocks/CU -> all co-resident.

typedef __attribute__((ext_vector_type(8))) short bf16x8;   // 8 bf16 = 4 VGPRs
typedef __attribute__((ext_vector_type(4))) float f32x4;

#define NROWS 8192
#define DDIM  128
#define BHALF 4096
#define CHUNK 32
#define NT    32                    // 32x32 grid of 256x256 tiles
#define NBLK  528                   // 32*33/2 upper-triangle tiles
// zn scaled by sqrt(2/ln2): acc = (2/ln2)*cos, exp(2cos) = exp2(acc)
#define SQRT_E2S 1.6986435980707531f
#define TWO_LN2  1.3862943611198906f
#define EXPDIAG  7.38905609893065f

static __device__ __forceinline__ unsigned short f2bf(float f) {
  unsigned int u = __float_as_uint(f);
  unsigned int r = (u + 0x7fffu + ((u >> 16) & 1u)) >> 16;   // RNE
  return (unsigned short)r;
}

static __device__ __forceinline__ void glds16(const unsigned short* g, unsigned short* l) {
  __builtin_amdgcn_global_load_lds((const __attribute__((address_space(1))) unsigned int*)g,
                                   (__attribute__((address_space(3))) unsigned int*)l,
                                   16, 0, 0);
}

// ---- Kernel 1: normalize (scaled) + fp32 pair-dots + zero sums/out -------
// Block b: waves 0,1 -> rows 2b,2b+1 (zi); waves 2,3 -> their partners (zj).
__global__ void norm_kernel(const float* __restrict__ zi, const float* __restrict__ zj,
                            unsigned short* __restrict__ zn,
                            float* __restrict__ row_sums, float* __restrict__ pos,
                            float* __restrict__ out) {
  __shared__ float2 xbuf[2][64];
  int wave = threadIdx.x >> 6;
  int lane = threadIdx.x & 63;
  int pi   = blockIdx.x * 2 + (wave & 1);           // pair index
  int row  = pi + (wave >> 1) * BHALF;
  const float* src = (row < BHALF) ? (zi + (size_t)row * DDIM)
                                   : (zj + (size_t)(row - BHALF) * DDIM);
  float2 v = *(const float2*)(src + 2 * lane);
  float ss = v.x * v.x + v.y * v.y;
  #pragma unroll
  for (int off = 1; off < 64; off <<= 1) ss += __shfl_xor(ss, off);
  float scale = SQRT_E2S / fmaxf(sqrtf(ss), 1e-8f);
  v.x *= scale; v.y *= scale;
  unsigned int lo = f2bf(v.x), hi = f2bf(v.y);
  ((unsigned int*)(zn + (size_t)row * DDIM))[lane] = lo | (hi << 16);

  if (wave >= 2) xbuf[wave - 2][lane] = v;
  __syncthreads();
  if (wave < 2) {                                    // d = (2/ln2)*cos(i, i+B)
    float2 w = xbuf[wave][lane];
    float d = v.x * w.x + v.y * w.y;
    #pragma unroll
    for (int off = 1; off < 64; off <<= 1) d += __shfl_xor(d, off);
    if (lane == 0) pos[pi] = d;
  }
  if (threadIdx.x < 4) row_sums[blockIdx.x * 4 + threadIdx.x] = 0.0f;
  if (blockIdx.x == 0 && threadIdx.x == 4) out[0] = 0.0f;
}

// ---- Kernel 2: upper-triangle sim + exp + row/col sums -------------------
// 528 blocks (triangle map), 256x256 tiles, 4 waves x 64 rows, A in regs,
// B in 32-col chunks double-buffered via global_load_lds (XOR swizzle).
__global__ __launch_bounds__(256, 3)
void sim_kernel(const unsigned short* __restrict__ zn, float* __restrict__ row_sums) {
  __shared__ unsigned short lds[2 * CHUNK * DDIM];   // 2 x 8 KB
  __shared__ float colsum[256];

  // linear block id -> upper-triangle (tx <= ty) over NT x NT
  int t = blockIdx.x;
  int tx = (int)((65.0f - sqrtf((float)(4225 - 8 * t))) * 0.5f);
  while ((tx + 1) * NT - ((tx + 1) * tx) / 2 <= t) ++tx;
  while (tx * NT - (tx * (tx - 1)) / 2 > t) --tx;
  const int ty = t - (tx * NT - (tx * (tx - 1)) / 2) + tx;
  const bool diag = (tx == ty);

  const int wave = threadIdx.x >> 6;
  const int lane = threadIdx.x & 63;
  const int l15  = lane & 15;
  const int quad = lane >> 4;

  const int row_base = tx * 256 + wave * 64;
  const int col_base = ty * 256;

  colsum[threadIdx.x] = 0.0f;

  // A fragments: A[m=l15][k=quad*8+j], 4 mi-tiles x 4 k-frags = 64 VGPRs
  bf16x8 a[4][4];
  const unsigned short* abase = zn + (size_t)(row_base + l15) * DDIM + quad * 8;
  #pragma unroll
  for (int mi = 0; mi < 4; ++mi)
    #pragma unroll
    for (int kf = 0; kf < 4; ++kf)
      a[mi][kf] = *(const bf16x8*)(abase + mi * 16 * DDIM + kf * 32);

  float rs[4][4];
  #pragma unroll
  for (int mi = 0; mi < 4; ++mi)
    #pragma unroll
    for (int r = 0; r < 4; ++r) rs[mi][r] = 0.0f;

  // Staging: buffer = 32 B-rows x 16 chunks of 16B; slot t2 -> row t2>>4,
  // chunk (t2&15)^(row&15) [XOR swizzle]. Two 256-lane issues per chunk.
  const int t0 = wave * 64 + lane;
  const int r0 = t0 >> 4,         c0 = (t0 & 15) ^ (r0 & 15);
  const int r1 = (t0 + 256) >> 4, c1 = (t0 & 15) ^ (r1 & 15);
  const unsigned short* gst0 = zn + (size_t)(col_base + r0) * DDIM + c0 * 8;
  const unsigned short* gst1 = zn + (size_t)(col_base + r1) * DDIM + c1 * 8;

  int rdoff[4];
  #pragma unroll
  for (int kf = 0; kf < 4; ++kf)
    rdoff[kf] = l15 * DDIM + (((quad + 4 * kf) ^ l15) << 3);

  glds16(gst0, lds + wave * 512);                    // prime chunk 0 -> buf 0
  glds16(gst1, lds + 2048 + wave * 512);
  __syncthreads();

  for (int ch = 0; ch < 8; ++ch) {
    const int buf = ch & 1;
    if (ch < 7) {                                    // stage chunk ch+1
      const unsigned short* g0 = gst0 + (size_t)(ch + 1) * CHUNK * DDIM;
      const unsigned short* g1 = gst1 + (size_t)(ch + 1) * CHUNK * DDIM;
      unsigned short* lb = lds + ((ch + 1) & 1) * 4096;
      glds16(g0, lb + wave * 512);
      glds16(g1, lb + 2048 + wave * 512);
    }
    const unsigned short* lb = lds + buf * 4096;
    #pragma unroll
    for (int ni = 0; ni < 2; ++ni) {
      bf16x8 b[4];
      #pragma unroll
      for (int kf = 0; kf < 4; ++kf)
        b[kf] = *(const bf16x8*)(lb + ni * 16 * DDIM + rdoff[kf]);
      f32x4 acc[4];
      #pragma unroll
      for (int mi = 0; mi < 4; ++mi) {
        f32x4 z = {0.0f, 0.0f, 0.0f, 0.0f};
        acc[mi] = __builtin_amdgcn_mfma_f32_16x16x32_bf16(a[mi][0], b[0], z, 0, 0, 0);
      }
      #pragma unroll
      for (int kf = 1; kf < 4; ++kf)
        #pragma unroll
        for (int mi = 0; mi < 4; ++mi)
          acc[mi] = __builtin_amdgcn_mfma_f32_16x16x32_bf16(a[mi][kf], b[kf], acc[mi], 0, 0, 0);
      // e feeds this row's sum and (off-diag) the transposed row via colsum.
      float cs = 0.0f;
      #pragma unroll
      for (int mi = 0; mi < 4; ++mi)
        #pragma unroll
        for (int r = 0; r < 4; ++r) {
          float e = __builtin_amdgcn_exp2f(acc[mi][r]);
          rs[mi][r] += e;
          cs += e;
        }
      if (!diag) {                                   // transpose contribution
        cs += __shfl_xor(cs, 16);
        cs += __shfl_xor(cs, 32);
        if (quad == 0)
          atomicAdd(&colsum[(ch * 2 + ni) * 16 + l15], cs);
      }
    }
    __syncthreads();
  }

  // Row side. C/D layout: col=l15, row=quad*4+reg.
  #pragma unroll
  for (int mi = 0; mi < 4; ++mi)
    #pragma unroll
    for (int r = 0; r < 4; ++r) {
      float v = rs[mi][r];
      v += __shfl_xor(v, 1);
      v += __shfl_xor(v, 2);
      v += __shfl_xor(v, 4);
      v += __shfl_xor(v, 8);
      if (l15 == 0)
        atomicAdd(&row_sums[row_base + mi * 16 + quad * 4 + r], v);
    }
  // Col side: one atomic per col per block (transposed rows).
  if (!diag)
    atomicAdd(&row_sums[col_base + threadIdx.x], colsum[threadIdx.x]);
}

// ---- Kernel 3: logs + mean (pos already fp32 from norm) ------------------
__global__ void finalize_kernel(const float* __restrict__ row_sums,
                                const float* __restrict__ pos,
                                float* __restrict__ out) {
  __shared__ float red[4];
  int i = blockIdx.x * 256 + threadIdx.x;            // grid 16 x 256 = 4096 pairs
  float si = row_sums[i] - EXPDIAG;
  float sp = row_sums[i + BHALF] - EXPDIAG;
  float v = logf(si) + logf(sp) - TWO_LN2 * pos[i];
  #pragma unroll
  for (int off = 1; off < 64; off <<= 1) v += __shfl_xor(v, off);
  int wave = threadIdx.x >> 6, lane = threadIdx.x & 63;
  if (lane == 0) red[wave] = v;
  __syncthreads();
  if (threadIdx.x == 0)
    atomicAdd(out, (red[0] + red[1] + red[2] + red[3]) * (1.0f / 8192.0f));
}

extern "C" void kernel_launch(void* const* d_in, const int* in_sizes, int n_in,
                              void* d_out, int out_size, void* d_ws, size_t ws_size,
                              hipStream_t stream) {
  const float* zi = (const float*)d_in[0];
  const float* zj = (const float*)d_in[1];
  char* ws = (char*)d_ws;
  unsigned short* zn = (unsigned short*)ws;                    // 2 MB
  float* row_sums = (float*)(ws + (size_t)NROWS * DDIM * 2);   // 32 KB
  float* pos      = (float*)(ws + (size_t)NROWS * DDIM * 2 + NROWS * 4);  // 16 KB
  float* out = (float*)d_out;

  norm_kernel<<<2048, 256, 0, stream>>>(zi, zj, zn, row_sums, pos, out);
  sim_kernel<<<NBLK, 256, 0, stream>>>(zn, row_sums);
  finalize_kernel<<<16, 256, 0, stream>>>(row_sums, pos, out);
}